// Round 10
// baseline (854.288 us; speedup 1.0000x reference)
//
#include <hip/hip_runtime.h>
#include <hip/hip_bf16.h>
#include <stdint.h>

#define H 256
#define G 4096
#define TK 32     // k1a tile rows
#define T0 64     // k0/k1b tile rows

typedef __attribute__((ext_vector_type(8))) short bf16x8;
typedef __attribute__((ext_vector_type(4))) float f32x4;

__device__ inline short f2bf(float f){
  union { float f; uint32_t u; } v; v.f = f;
  uint32_t r = (v.u + 0x7FFFu + ((v.u >> 16) & 1u)) >> 16;
  return (short)(uint16_t)r;
}
__device__ inline float bf2f(short s){
  union { float f; uint32_t u; } v; v.u = ((uint32_t)(uint16_t)s) << 16;
  return v.f;
}
__device__ inline float sigmoidf_(float x){ return 1.f / (1.f + __expf(-x)); }

// LDS-only barrier: does NOT drain vmcnt, so in-flight global loads/atomics continue.
__device__ inline void ldsbar(){
  asm volatile("s_waitcnt lgkmcnt(0)" ::: "memory");
  __builtin_amdgcn_s_barrier();
}

// ---------------- weight conversion f32 -> bf16 ----------------
__global__ void conv_w(const float* __restrict__ w1, const float* __restrict__ wih,
                       const float* __restrict__ whh,
                       short* __restrict__ o1, short* __restrict__ oih, short* __restrict__ ohh){
  int i = blockIdx.x * 256 + threadIdx.x;
  if (i < H*H) o1[i] = f2bf(w1[i]);
  if (i < 3*H*H){ oih[i] = f2bf(wih[i]); ohh[i] = f2bf(whh[i]); }
}

// ---------------- K0: mean-pool sums + counts + write x_bf16 ----------------
__global__ __launch_bounds__(512, 6) void k0_pool(const float* __restrict__ x, const int* __restrict__ batch,
                                                  float* __restrict__ pool, float* __restrict__ counts,
                                                  short* __restrict__ xbf, int nNodes){
  __shared__ int   ng[T0];
  __shared__ float Pacc[8][H];
  __shared__ float Cacc[8];
  __shared__ int   spanSh;

  const int t = threadIdx.x;
  const int base = blockIdx.x * T0;
  const int c4 = (t & 63) * 4;
  const int r0 = (t >> 6) * 8;   // 8 row-groups of 8 rows

  // issue the big loads FIRST so they overlap all setup
  float4 v[8];
  #pragma unroll
  for (int i = 0; i < 8; ++i){
    int node = base + r0 + i;
    if (node < nNodes) v[i] = *(const float4*)(x + (size_t)node*H + c4);
    else v[i] = make_float4(0.f,0.f,0.f,0.f);
  }

  if (t < T0) ng[t] = (base + t < nNodes) ? batch[base + t] : -1;
  for (int u = t; u < 8*H; u += 512) ((float*)Pacc)[u] = 0.f;
  if (t < 8) Cacc[t] = 0.f;
  __syncthreads();

  if (t == 64){
    int lg = ng[0];
    for (int i = 1; i < T0; ++i){ int g = ng[i]; if (g >= 0) lg = g; }
    spanSh = (ng[0] >= 0) ? (lg - ng[0]) : -1;
  }

  // write bf16 copy of x
  if (xbf){
    #pragma unroll
    for (int i = 0; i < 8; ++i){
      int node = base + r0 + i;
      if (node < nNodes){
        ushort4 o;
        o.x = (uint16_t)f2bf(v[i].x); o.y = (uint16_t)f2bf(v[i].y);
        o.z = (uint16_t)f2bf(v[i].z); o.w = (uint16_t)f2bf(v[i].w);
        *(ushort4*)(xbf + (size_t)node*H + c4) = o;
      }
    }
  }
  __syncthreads();

  const int g0 = ng[0];
  const bool useLds = (spanSh >= 0) && (spanSh < 8);

  float ax=0.f, ay=0.f, az=0.f, aw=0.f;
  int cur = ng[r0];
  if (cur >= 0){
    #pragma unroll
    for (int i = 0; i < 8; ++i){
      int g = ng[r0 + i];
      if (g < 0) break;
      if (g != cur){
        if (useLds){
          atomicAdd(&Pacc[cur-g0][c4], ax);   atomicAdd(&Pacc[cur-g0][c4+1], ay);
          atomicAdd(&Pacc[cur-g0][c4+2], az); atomicAdd(&Pacc[cur-g0][c4+3], aw);
        } else {
          atomicAdd(&pool[(size_t)cur*H + c4], ax);   atomicAdd(&pool[(size_t)cur*H + c4+1], ay);
          atomicAdd(&pool[(size_t)cur*H + c4+2], az); atomicAdd(&pool[(size_t)cur*H + c4+3], aw);
        }
        ax=ay=az=aw=0.f; cur = g;
      }
      ax += v[i].x; ay += v[i].y; az += v[i].z; aw += v[i].w;
    }
    if (useLds){
      atomicAdd(&Pacc[cur-g0][c4], ax);   atomicAdd(&Pacc[cur-g0][c4+1], ay);
      atomicAdd(&Pacc[cur-g0][c4+2], az); atomicAdd(&Pacc[cur-g0][c4+3], aw);
    } else {
      atomicAdd(&pool[(size_t)cur*H + c4], ax);   atomicAdd(&pool[(size_t)cur*H + c4+1], ay);
      atomicAdd(&pool[(size_t)cur*H + c4+2], az); atomicAdd(&pool[(size_t)cur*H + c4+3], aw);
    }
  }
  if (t < T0 && ng[t] >= 0){
    if (useLds) atomicAdd(&Cacc[ng[t]-g0], 1.f);
    else        atomicAdd(&counts[ng[t]], 1.f);
  }
  __syncthreads();

  if (useLds){
    int nr = spanSh + 1;
    for (int u = t; u < nr*H; u += 512){
      int r = u >> 8, c = u & 255;
      float vv = Pacc[r][c];
      if (vv != 0.f) atomicAdd(&pool[(size_t)(g0+r)*H + c], vv);
    }
    if (t < nr && Cacc[t] != 0.f) atomicAdd(&counts[g0 + t], Cacc[t]);
  }
}

// ---------------- K0b: repr = pool / max(counts,1) ----------------
__global__ void k0b_div(const float* __restrict__ pool, const float* __restrict__ counts,
                        float* __restrict__ repr){
  size_t i = (size_t)blockIdx.x * 256 + threadIdx.x;
  int g = (int)(i >> 8);
  repr[i] = pool[i] / fmaxf(counts[g], 1.f);
}

// ---------------- KT: hg[g] = W1 * bf16(repr[g]) + b1 ----------------
__global__ __launch_bounds__(256) void kT_hg(const float* __restrict__ repr,
    const short* __restrict__ w1bf, const float* __restrict__ b1,
    float* __restrict__ hg){
  __shared__ short Ar[16][H + 8];
  const int t    = threadIdx.x;
  const int wid  = t >> 6;
  const int lane = t & 63;
  const int l15  = lane & 15;
  const int l4   = lane >> 4;
  const int g0   = blockIdx.x * 16;

  for (int u = t; u < 16*32; u += 256){
    int row = u >> 5, cg = u & 31;
    int c0 = cg * 8;
    const float4* rp = (const float4*)(repr + (size_t)(g0+row)*H + c0);
    float4 r0 = rp[0], r1 = rp[1];
    bf16x8 o;
    o[0]=f2bf(r0.x); o[1]=f2bf(r0.y); o[2]=f2bf(r0.z); o[3]=f2bf(r0.w);
    o[4]=f2bf(r1.x); o[5]=f2bf(r1.y); o[6]=f2bf(r1.z); o[7]=f2bf(r1.w);
    *(bf16x8*)(&Ar[row][c0]) = o;
  }
  __syncthreads();

  f32x4 acc[4];
  #pragma unroll
  for (int i = 0; i < 4; ++i) acc[i] = (f32x4){0.f,0.f,0.f,0.f};
  #pragma unroll
  for (int kc = 0; kc < 8; ++kc){
    bf16x8 a = *(bf16x8*)(&Ar[l15][kc*32 + l4*8]);
    #pragma unroll
    for (int nt = 0; nt < 4; ++nt){
      int col = wid*64 + nt*16 + l15;
      bf16x8 b = *(const bf16x8*)(w1bf + (size_t)col*H + kc*32 + l4*8);
      acc[nt] = __builtin_amdgcn_mfma_f32_16x16x32_bf16(a, b, acc[nt], 0, 0, 0);
    }
  }
  #pragma unroll
  for (int nt = 0; nt < 4; ++nt){
    int col = wid*64 + nt*16 + l15;
    float b1v = b1[col];
    #pragma unroll
    for (int j = 0; j < 4; ++j){
      int row = l4*4 + j;
      hg[(size_t)(g0+row)*H + col] = acc[nt][j] + b1v;
    }
  }
}

// ---------------- K1a: gate scores, col-split persistent GEMM ----------------
// sgate[node] += sum over this block's 128 cols of w2[c]*relu((W1*bf16(x))[c] + hg[g][c])
// 1024 blocks (exactly 4/CU), 256 thr (4 waves), 32 cols/wave, ONE barrier per tile.
template<bool BF>
__global__ __launch_bounds__(256) __attribute__((amdgpu_waves_per_eu(3, 4)))
void k1a_gate(
    const float* __restrict__ xf32, const short* __restrict__ xbf,
    const int* __restrict__ batch, const float* __restrict__ hg,
    const short* __restrict__ w1bf, const float* __restrict__ w2,
    float* __restrict__ sgate,
    int nNodes, int nTiles, int nChains){

  __shared__ short Ain[2][TK][H + 8];   // 33.8 KB double-buffered x tiles
  __shared__ int   ngS[2][TK];

  const int t    = threadIdx.x;
  const int wid  = t >> 6;      // 0..3
  const int lane = t & 63;
  const int l15  = lane & 15;
  const int l4   = lane >> 4;

  const int ch    = blockIdx.x >= nChains;          // col half (pair b, b+nChains share XCD)
  const int chain = ch ? blockIdx.x - nChains : blockIdx.x;
  const int colB  = ch*128 + wid*32;                // this wave's 32 cols

  const int tile0 = (int)(((long long)chain * nTiles) / nChains);
  const int tile1 = (int)(((long long)(chain+1) * nTiles) / nChains);
  if (tile0 >= tile1) return;

  // W1 slices (64 VGPR), loaded once per block
  bf16x8 Bf0[8], Bf1[8];
  {
    const short* wp0 = w1bf + (size_t)(colB + l15)*H + l4*8;
    #pragma unroll
    for (int kc = 0; kc < 8; ++kc){
      Bf0[kc] = *(const bf16x8*)(wp0 + kc*32);
      Bf1[kc] = *(const bf16x8*)(wp0 + 16*H + kc*32);
    }
  }
  const float w2v0 = w2[colB + l15];
  const float w2v1 = w2[colB + 16 + l15];

  // ---- prefetch state: thread stages rows {t>>5 + 8q}, col chunk (t&31)*8 ----
  const int srow = t >> 5;
  const int scol = (t & 31) * 8;
  bf16x8 xv[4];
  float4 xf[4][2];
  int ngv = -1;

  auto issueT = [&](int tile){
    int base = tile * TK;
    #pragma unroll
    for (int q = 0; q < 4; ++q){
      int node = base + srow + q*8;
      if constexpr (BF){
        xv[q] = (node < nNodes) ? *(const bf16x8*)(xbf + (size_t)node*H + scol) : (bf16x8)0;
      } else {
        if (node < nNodes){
          const float4* xp = (const float4*)(xf32 + (size_t)node*H + scol);
          xf[q][0] = xp[0]; xf[q][1] = xp[1];
        } else { xf[q][0] = make_float4(0.f,0.f,0.f,0.f); xf[q][1] = make_float4(0.f,0.f,0.f,0.f); }
      }
    }
    if (t < TK){
      int node = base + t;
      ngv = (node < nNodes) ? batch[node] : -1;
    }
  };
  auto stageT = [&](int buf){
    #pragma unroll
    for (int q = 0; q < 4; ++q){
      bf16x8 o;
      if constexpr (BF) o = xv[q];
      else {
        float4 a = xf[q][0], c = xf[q][1];
        o[0]=f2bf(a.x); o[1]=f2bf(a.y); o[2]=f2bf(a.z); o[3]=f2bf(a.w);
        o[4]=f2bf(c.x); o[5]=f2bf(c.y); o[6]=f2bf(c.z); o[7]=f2bf(c.w);
      }
      *(bf16x8*)(&Ain[buf][srow + q*8][scol]) = o;
    }
    if (t < TK) ngS[buf][t] = ngv;
  };

  // prologue
  issueT(tile0);
  stageT(0);
  if (tile0 + 1 < tile1) issueT(tile0 + 1);

  int cur = 0;
  for (int tile = tile0; tile < tile1; ++tile, cur ^= 1){
    ldsbar();   // Ain[cur]/ngS[cur] visible; all reads of Ain[cur^1] from prev iter done

    // hg gather issued EARLY (overlaps MFMA)
    int gr[2][4];
    float hv0[2][4], hv1[2][4];
    #pragma unroll
    for (int r = 0; r < 2; ++r)
      #pragma unroll
      for (int j = 0; j < 4; ++j){
        int g = ngS[cur][r*16 + l4*4 + j];
        gr[r][j] = g;
        if (g >= 0){
          const float* hgr = hg + (size_t)g*H + colB;
          hv0[r][j] = hgr[l15]; hv1[r][j] = hgr[16 + l15];
        } else { hv0[r][j] = 0.f; hv1[r][j] = 0.f; }
      }

    // MFMA: rows 0..31, this wave's 32 cols
    f32x4 acc0[2], acc1[2];
    #pragma unroll
    for (int r = 0; r < 2; ++r){ acc0[r] = (f32x4){0.f,0.f,0.f,0.f}; acc1[r] = (f32x4){0.f,0.f,0.f,0.f}; }
    #pragma unroll
    for (int kc = 0; kc < 8; ++kc){
      #pragma unroll
      for (int r = 0; r < 2; ++r){
        bf16x8 a = *(bf16x8*)(&Ain[cur][r*16 + l15][kc*32 + l4*8]);
        acc0[r] = __builtin_amdgcn_mfma_f32_16x16x32_bf16(a, Bf0[kc], acc0[r], 0, 0, 0);
        acc1[r] = __builtin_amdgcn_mfma_f32_16x16x32_bf16(a, Bf1[kc], acc1[r], 0, 0, 0);
      }
    }

    // stage next tile into other buffer; issue loads for tile+2
    if (tile + 1 < tile1){
      stageT(cur ^ 1);
      if (tile + 2 < tile1) issueT(tile + 2);
    }

    // epilogue: partial w2·relu(acc+hg) over 32 cols, 16-lane reduce, atomic to sgate
    float p[2][4];
    #pragma unroll
    for (int r = 0; r < 2; ++r)
      #pragma unroll
      for (int j = 0; j < 4; ++j){
        float h0 = fmaxf(acc0[r][j] + hv0[r][j], 0.f);
        float h1 = fmaxf(acc1[r][j] + hv1[r][j], 0.f);
        p[r][j] = w2v0*h0 + w2v1*h1;
      }
    #pragma unroll
    for (int off = 1; off < 16; off <<= 1){
      #pragma unroll
      for (int r = 0; r < 2; ++r)
        #pragma unroll
        for (int j = 0; j < 4; ++j) p[r][j] += __shfl_xor(p[r][j], off);
    }
    if (l15 == 0){
      int base = tile * TK;
      #pragma unroll
      for (int r = 0; r < 2; ++r)
        #pragma unroll
        for (int j = 0; j < 4; ++j){
          if (gr[r][j] >= 0)
            atomicAdd(&sgate[base + r*16 + l4*4 + j], p[r][j]);
        }
    }
  }
}

// ---------------- K1b: streaming weighted pooling (k0-style) ----------------
// gate = sigmoid(sgate[node] + b2); pool[g] += gate * bf16(x[node])
template<bool BF>
__global__ __launch_bounds__(512, 6) void k1b_pool(
    const float* __restrict__ xf32, const short* __restrict__ xbf,
    const int* __restrict__ batch, const float* __restrict__ sgate,
    const float* __restrict__ b2p, float* __restrict__ pool, int nNodes){

  __shared__ int   ng[T0];
  __shared__ float gs[T0];
  __shared__ float Pacc[8][H];
  __shared__ int   spanSh;

  const int t = threadIdx.x;
  const int base = blockIdx.x * T0;
  const int c4 = (t & 63) * 4;
  const int r0 = (t >> 6) * 8;

  // issue x loads first
  ushort4 u[8];
  float4  vf[8];
  #pragma unroll
  for (int i = 0; i < 8; ++i){
    int node = base + r0 + i;
    if constexpr (BF){
      u[i] = (node < nNodes) ? *(const ushort4*)(xbf + (size_t)node*H + c4)
                             : make_ushort4(0,0,0,0);
    } else {
      vf[i] = (node < nNodes) ? *(const float4*)(xf32 + (size_t)node*H + c4)
                              : make_float4(0.f,0.f,0.f,0.f);
    }
  }

  const float b2v = b2p[0];
  if (t < T0){
    int node = base + t;
    if (node < nNodes){
      ng[t] = batch[node];
      gs[t] = sigmoidf_(sgate[node] + b2v);
    } else { ng[t] = -1; gs[t] = 0.f; }
  }
  for (int w = t; w < 8*H; w += 512) ((float*)Pacc)[w] = 0.f;
  __syncthreads();

  if (t == 64){
    int lg = ng[0];
    for (int i = 1; i < T0; ++i){ int g = ng[i]; if (g >= 0) lg = g; }
    spanSh = (ng[0] >= 0) ? (lg - ng[0]) : -1;
  }
  __syncthreads();

  const int g0 = ng[0];
  const bool useLds = (spanSh >= 0) && (spanSh < 8);

  float ax=0.f, ay=0.f, az=0.f, aw=0.f;
  int cur = ng[r0];
  if (cur >= 0){
    #pragma unroll
    for (int i = 0; i < 8; ++i){
      int g = ng[r0 + i];
      if (g < 0) break;
      if (g != cur){
        if (useLds){
          atomicAdd(&Pacc[cur-g0][c4], ax);   atomicAdd(&Pacc[cur-g0][c4+1], ay);
          atomicAdd(&Pacc[cur-g0][c4+2], az); atomicAdd(&Pacc[cur-g0][c4+3], aw);
        } else {
          atomicAdd(&pool[(size_t)cur*H + c4], ax);   atomicAdd(&pool[(size_t)cur*H + c4+1], ay);
          atomicAdd(&pool[(size_t)cur*H + c4+2], az); atomicAdd(&pool[(size_t)cur*H + c4+3], aw);
        }
        ax=ay=az=aw=0.f; cur = g;
      }
      float gv = gs[r0 + i];
      if constexpr (BF){
        ax += gv * bf2f((short)u[i].x); ay += gv * bf2f((short)u[i].y);
        az += gv * bf2f((short)u[i].z); aw += gv * bf2f((short)u[i].w);
      } else {
        ax += gv * bf2f(f2bf(vf[i].x)); ay += gv * bf2f(f2bf(vf[i].y));
        az += gv * bf2f(f2bf(vf[i].z)); aw += gv * bf2f(f2bf(vf[i].w));
      }
    }
    if (useLds){
      atomicAdd(&Pacc[cur-g0][c4], ax);   atomicAdd(&Pacc[cur-g0][c4+1], ay);
      atomicAdd(&Pacc[cur-g0][c4+2], az); atomicAdd(&Pacc[cur-g0][c4+3], aw);
    } else {
      atomicAdd(&pool[(size_t)cur*H + c4], ax);   atomicAdd(&pool[(size_t)cur*H + c4+1], ay);
      atomicAdd(&pool[(size_t)cur*H + c4+2], az); atomicAdd(&pool[(size_t)cur*H + c4+3], aw);
    }
  }
  __syncthreads();

  if (useLds){
    int nr = spanSh + 1;
    for (int w = t; w < nr*H; w += 512){
      int r = w >> 8, c = w & 255;
      float vv = Pacc[r][c];
      if (vv != 0.f) atomicAdd(&pool[(size_t)(g0+r)*H + c], vv);
    }
  }
}

// ---------------- K2: fused GRU over 16 graphs/block ----------------
__global__ __launch_bounds__(256) void k2_gru(const float* __restrict__ pool,
    const float* __restrict__ counts, const float* __restrict__ repr_in,
    const short* __restrict__ wihbf, const short* __restrict__ whhbf,
    const float* __restrict__ bih, const float* __restrict__ bhh,
    float* __restrict__ repr_out){

  __shared__ short Anew[16][H + 8];
  __shared__ short Aold[16][H + 8];
  __shared__ float hold[16][H];
  __shared__ float srz[16][2*H];
  __shared__ float sni[16][H];
  __shared__ float snh[16][H];

  const int t    = threadIdx.x;
  const int wid  = t >> 6;
  const int lane = t & 63;
  const int l15  = lane & 15;
  const int l4   = lane >> 4;
  const int g0   = blockIdx.x * 16;

  for (int u = t; u < 16*H; u += 256){
    int row = u >> 8, c = u & 255;
    int g = g0 + row;
    float cnt = fmaxf(counts[g], 1.f);
    float rin = repr_in[(size_t)g*H + c];
    float nr  = pool[(size_t)g*H + c] / cnt;
    Anew[row][c] = f2bf(nr);
    Aold[row][c] = f2bf(rin);
    hold[row][c] = rin;
  }
  __syncthreads();

  f32x4 ai[12], ah[12];
  #pragma unroll
  for (int i = 0; i < 12; ++i){ ai[i] = (f32x4){0.f,0.f,0.f,0.f}; ah[i] = (f32x4){0.f,0.f,0.f,0.f}; }

  for (int kc = 0; kc < 8; ++kc){
    bf16x8 an = *(bf16x8*)(&Anew[l15][kc*32 + l4*8]);
    bf16x8 ao = *(bf16x8*)(&Aold[l15][kc*32 + l4*8]);
    #pragma unroll
    for (int nt = 0; nt < 12; ++nt){
      int n = wid*192 + nt*16 + l15;
      bf16x8 bi = *(const bf16x8*)(wihbf + (size_t)n*H + kc*32 + l4*8);
      bf16x8 bh = *(const bf16x8*)(whhbf + (size_t)n*H + kc*32 + l4*8);
      ai[nt] = __builtin_amdgcn_mfma_f32_16x16x32_bf16(an, bi, ai[nt], 0, 0, 0);
      ah[nt] = __builtin_amdgcn_mfma_f32_16x16x32_bf16(ao, bh, ah[nt], 0, 0, 0);
    }
  }

  #pragma unroll
  for (int nt = 0; nt < 12; ++nt){
    int n = wid*192 + nt*16 + l15;
    float bi = bih[n], bh = bhh[n];
    #pragma unroll
    for (int r = 0; r < 4; ++r){
      int row = l4*4 + r;
      float si = ai[nt][r] + bi;
      float sh = ah[nt][r] + bh;
      if (n < 2*H) srz[row][n] = si + sh;
      else { sni[row][n - 2*H] = si; snh[row][n - 2*H] = sh; }
    }
  }
  __syncthreads();

  for (int u = t; u < 16*H; u += 256){
    int row = u >> 8, c = u & 255;
    float rr = sigmoidf_(srz[row][c]);
    float zz = sigmoidf_(srz[row][H + c]);
    float nn = tanhf(sni[row][c] + rr * snh[row][c]);
    float hv = (1.f - zz) * nn + zz * hold[row][c];
    repr_out[(size_t)(g0 + row)*H + c] = fmaxf(hv, 0.f);
  }
}

extern "C" void kernel_launch(void* const* d_in, const int* in_sizes, int n_in,
                              void* d_out, int out_size, void* d_ws, size_t ws_size,
                              hipStream_t stream){
  const float* x    = (const float*)d_in[0];
  const float* w1   = (const float*)d_in[1];
  const float* b1   = (const float*)d_in[2];
  const float* w2   = (const float*)d_in[3];
  const float* b2   = (const float*)d_in[4];
  const float* wih  = (const float*)d_in[5];
  const float* whh  = (const float*)d_in[6];
  const float* bih  = (const float*)d_in[7];
  const float* bhh  = (const float*)d_in[8];
  const int*   batch= (const int*)d_in[9];
  const int N = in_sizes[9];

  char* ws = (char*)d_ws;
  short* w1bf   = (short*)(ws + 0);            // 128 KB
  short* wihbf  = (short*)(ws + (1u<<17));     // 384 KB @128K
  short* whhbf  = (short*)(ws + (1u<<19));     // 384 KB @512K
  float* counts = (float*)(ws + 917504);       // 16 KB @896K
  float* pool   = (float*)(ws + (1u<<20));     // 4 MB @1M
  float* repr   = (float*)(ws + (1u<<20) + (1u<<22)); // 4 MB @5M
  float* sgate  = (float*)(ws + (9u<<20));     // 2 MB @9M
  float* hg     = (float*)d_out;               // 4 MB, dead before final k2 writes output
  float* outp   = (float*)d_out;

  const size_t XBF_OFF = (size_t)16u << 20;    // 16 MB
  const bool useXbf = ws_size >= XBF_OFF + (size_t)N * H * sizeof(short);
  short* xbf = useXbf ? (short*)(ws + XBF_OFF) : nullptr;

  const int nTiles  = (N + TK - 1) / TK;       // 15625
  const int nChains = 512;
  const int nBlk1a  = nChains * 2;             // 1024 blocks = exactly 4/CU resident
  const int nBlk0   = (N + T0 - 1) / T0;

  conv_w<<<768, 256, 0, stream>>>(w1, wih, whh, w1bf, wihbf, whhbf);

  hipMemsetAsync(counts, 0, G*sizeof(float), stream);
  hipMemsetAsync(pool, 0, (size_t)G*H*sizeof(float), stream);
  k0_pool<<<nBlk0, 512, 0, stream>>>(x, batch, pool, counts, xbf, N);
  k0b_div<<<G*H/256, 256, 0, stream>>>(pool, counts, repr);

  for (int ts = 0; ts < 2; ++ts){
    kT_hg<<<G/16, 256, 0, stream>>>(repr, w1bf, b1, hg);
    hipMemsetAsync(sgate, 0, (size_t)N*sizeof(float), stream);
    hipMemsetAsync(pool, 0, (size_t)G*H*sizeof(float), stream);
    if (useXbf){
      k1a_gate<true><<<nBlk1a, 256, 0, stream>>>(x, xbf, batch, hg, w1bf, w2, sgate, N, nTiles, nChains);
      k1b_pool<true><<<nBlk0, 512, 0, stream>>>(x, xbf, batch, sgate, b2, pool, N);
    } else {
      k1a_gate<false><<<nBlk1a, 256, 0, stream>>>(x, xbf, batch, hg, w1bf, w2, sgate, N, nTiles, nChains);
      k1b_pool<false><<<nBlk0, 512, 0, stream>>>(x, xbf, batch, sgate, b2, pool, N);
    }
    k2_gru<<<G/16, 256, 0, stream>>>(pool, counts, repr, wihbf, whhbf, bih, bhh,
                                     (ts == 0) ? repr : outp);
  }
}